// Round 9
// baseline (338.238 us; speedup 1.0000x reference)
//
#include <hip/hip_runtime.h>
#include <hip/hip_bf16.h>

typedef __bf16 bf16;
typedef __bf16 bf16x8 __attribute__((ext_vector_type(8)));
typedef float floatx4 __attribute__((ext_vector_type(4)));

// B=2, T=512, C=8, D=512, H=8, dk=64. M = B*T*C = 8192.
// Inputs fp32 (dict order), output fp32.
// ws: X | Q | K | V^T (each 8192*512 bf16 = 8.39MB) | WT (4x512x512 bf16, 2MB)
// Q,K: [hd][t][d]; V^T: [hd][d][t]; hd = b*64+h*8+c.  Total 35.6 MB (proven).

union Pack8 { bf16 h[8]; uint4 u; };

__device__ __forceinline__ bf16x8 loadA8(const float* p) {
    float4 a = *(const float4*)p;
    float4 b = *(const float4*)(p + 4);
    Pack8 r;
    r.h[0] = (bf16)a.x; r.h[1] = (bf16)a.y; r.h[2] = (bf16)a.z; r.h[3] = (bf16)a.w;
    r.h[4] = (bf16)b.x; r.h[5] = (bf16)b.y; r.h[6] = (bf16)b.z; r.h[7] = (bf16)b.w;
    return *(bf16x8*)&r.u;
}
__device__ __forceinline__ bf16x8 loadA8(const bf16* p) {
    Pack8 r; r.u = *(const uint4*)p; return *(bf16x8*)&r.u;
}

// ---------------- weight transpose W[K][N] fp32 -> WT[N][K] bf16 -------------
__global__ __launch_bounds__(256) void wtr_kernel(
    const float* __restrict__ Wq, const float* __restrict__ Wk,
    const float* __restrict__ Wv, const float* __restrict__ Wo,
    bf16* __restrict__ WT)
{
    __shared__ float Ts[64][65];
    const int tid = threadIdx.x;
    const int k0 = blockIdx.x * 64;
    const int n0 = blockIdx.y * 64;
    const int z  = blockIdx.z;
    const float* W = (z == 0) ? Wq : (z == 1) ? Wk : (z == 2) ? Wv : Wo;
    bf16* O = WT + (size_t)z * 512 * 512;
    #pragma unroll
    for (int i = 0; i < 16; i++) {
        const int r = i * 4 + (tid >> 6), c = tid & 63;
        Ts[r][c] = W[(size_t)(k0 + r) * 512 + n0 + c];
    }
    __syncthreads();
    #pragma unroll
    for (int i = 0; i < 16; i++) {
        const int a = i * 4 + (tid >> 6), c = tid & 63;
        O[(size_t)(n0 + a) * 512 + k0 + c] = (bf16)Ts[c][a];
    }
}

// ---------------- LDS-free GEMM, 32x32 wave-tiles ----------------------------
// Block 256 = 4 waves covering 64x64; per wave K-step: A loads + 2 b128 B
// loads + 4 MFMA. A fp32 (inline cvt) or bf16. layout: 0 Q/K, 1 V^T, 2 fp32.
template<typename TA, typename TO>
__device__ __forceinline__ void gemm32_body(
    const TA* __restrict__ A, const bf16* __restrict__ BT,
    const float* __restrict__ bias, TO* __restrict__ out,
    int mblk, int nblk, int layout)
{
    const int tid  = threadIdx.x;
    const int lane = tid & 63;
    const int wave = tid >> 6;
    const int quad = lane >> 4;
    const int l16  = lane & 15;
    const int wr = (wave >> 1) * 32;
    const int wc = (wave & 1) * 32;

    const TA*   Ap = A  + (size_t)(mblk + wr + l16) * 512 + quad * 8;
    const bf16* Bp = BT + (size_t)(nblk + wc + l16) * 512 + quad * 8;

    floatx4 acc[2][2] = {};
    #pragma unroll 2
    for (int k0 = 0; k0 < 512; k0 += 32) {
        bf16x8 a[2], b[2];
        #pragma unroll
        for (int mt = 0; mt < 2; mt++)
            a[mt] = loadA8(Ap + (size_t)mt * 16 * 512 + k0);
        #pragma unroll
        for (int nt = 0; nt < 2; nt++)
            b[nt] = loadA8(Bp + (size_t)nt * 16 * 512 + k0);
        #pragma unroll
        for (int mt = 0; mt < 2; mt++)
            #pragma unroll
            for (int nt = 0; nt < 2; nt++)
                acc[mt][nt] = __builtin_amdgcn_mfma_f32_16x16x32_bf16(
                    a[mt], b[nt], acc[mt][nt], 0, 0, 0);
    }

    #pragma unroll
    for (int mt = 0; mt < 2; mt++) {
        #pragma unroll
        for (int nt = 0; nt < 2; nt++) {
            const int colg = nblk + wc + nt * 16 + l16;
            const float bb = bias[colg];
            #pragma unroll
            for (int r = 0; r < 4; r++) {
                const int rowg = mblk + wr + mt * 16 + quad * 4 + r;
                const float v = acc[mt][nt][r] + bb;
                if (layout == 2) {
                    out[(size_t)rowg * 512 + colg] = (TO)v;
                } else {
                    const int bb_ = rowg >> 12;
                    const int t = (rowg >> 3) & 511;
                    const int c = rowg & 7;
                    const int h = colg >> 6;
                    const int d = colg & 63;
                    const int hd = bb_ * 64 + h * 8 + c;
                    const size_t addr = (layout == 0)
                        ? ((size_t)hd * 512 + t) * 64 + d
                        : ((size_t)hd * 64 + d) * 512 + t;
                    out[addr] = (TO)v;
                }
            }
        }
    }
}

// fused QKV: grid (128, 8, 3)
__global__ __launch_bounds__(256) void qkv_kernel(
    const float* __restrict__ qin, const float* __restrict__ kin,
    const float* __restrict__ vin, const bf16* __restrict__ WT,
    const float* __restrict__ Bq, const float* __restrict__ Bk,
    const float* __restrict__ Bv,
    bf16* __restrict__ Qws, bf16* __restrict__ Kws, bf16* __restrict__ Vtws)
{
    const int z = blockIdx.z;
    const float *A, *bias; bf16* O; int layout;
    if (z == 0)      { A = qin; bias = Bq; O = Qws;  layout = 0; }
    else if (z == 1) { A = kin; bias = Bk; O = Kws;  layout = 0; }
    else             { A = vin; bias = Bv; O = Vtws; layout = 1; }
    gemm32_body<float, bf16>(A, WT + (size_t)z * 262144, bias, O,
                             blockIdx.x * 64, blockIdx.y * 64, layout);
}

// output projection: grid (128, 8), fp32 out
__global__ __launch_bounds__(256) void out_kernel(
    const bf16* __restrict__ X, const bf16* __restrict__ WT,
    const float* __restrict__ Bo, float* __restrict__ out)
{
    gemm32_body<bf16, float>(X, WT + (size_t)3 * 262144, Bo, out,
                             blockIdx.x * 64, blockIdx.y * 64, 2);
}

// ---------------- attention: one block = one head x 16 queries ---------------
// Mask staged as bf16 additive bias (coalesced int4 loads); S lives in
// registers (MFMA C-layout); row softmax via shfl_xor + tiny LDS; P -> LDS
// bf16 once; then PV.
#define PST 520

__global__ __launch_bounds__(256) void attn_kernel(
    const bf16* __restrict__ Qws, const bf16* __restrict__ Kws,
    const bf16* __restrict__ Vtws, const int* __restrict__ mask,
    bf16* __restrict__ Xws)
{
    __shared__ bf16 Msm[16][PST];
    __shared__ bf16 Psm[16][PST];
    __shared__ float redM[4][16];
    __shared__ float redS[4][16];
    const int tid  = threadIdx.x;
    const int wave = tid >> 6;
    const int lane = tid & 63;
    const int quad = lane >> 4;
    const int l16  = lane & 15;
    const int qt = blockIdx.x;   // 0..31
    const int hd = blockIdx.y;   // 0..127
    const int q0 = qt * 16;
    const int b = hd >> 6;
    const int h = (hd >> 3) & 7;
    const int c = hd & 7;

    // stage mask rows q0..q0+15 as bias (0 / -1e9), coalesced
    {
        const int* mp = mask + ((size_t)b * 512 + q0) * 512;
        #pragma unroll
        for (int it = 0; it < 8; it++) {
            const int idx = (it * 256 + tid) * 4;
            const int4 mv = *(const int4*)(mp + idx);
            const int row = idx >> 9, col = idx & 511;
            union { bf16 h[4]; unsigned long long u; } pk;
            pk.h[0] = (mv.x == 0) ? (bf16)(-1.0e9f) : (bf16)0.0f;
            pk.h[1] = (mv.y == 0) ? (bf16)(-1.0e9f) : (bf16)0.0f;
            pk.h[2] = (mv.z == 0) ? (bf16)(-1.0e9f) : (bf16)0.0f;
            pk.h[3] = (mv.w == 0) ? (bf16)(-1.0e9f) : (bf16)0.0f;
            *(unsigned long long*)&Msm[row][col] = pk.u;
        }
    }

    // Q fragments (global)
    const bf16* Qh = Qws + (size_t)hd * 512 * 64;
    const bf16* Kh = Kws + (size_t)hd * 512 * 64;
    bf16x8 aq0 = *(const bf16x8*)(Qh + (size_t)(q0 + l16) * 64 + quad * 8);
    bf16x8 aq1 = *(const bf16x8*)(Qh + (size_t)(q0 + l16) * 64 + 32 + quad * 8);
    __syncthreads();

    // phase 1: S in registers; wave w covers keys [w*128, w*128+128)
    float sv[8][4];
    float mx[4] = {-3.0e38f, -3.0e38f, -3.0e38f, -3.0e38f};
    #pragma unroll
    for (int nt = 0; nt < 8; nt++) {
        const int s0 = wave * 128 + nt * 16;
        bf16x8 bk0 = *(const bf16x8*)(Kh + (size_t)(s0 + l16) * 64 + quad * 8);
        bf16x8 bk1 = *(const bf16x8*)(Kh + (size_t)(s0 + l16) * 64 + 32 + quad * 8);
        floatx4 s = {};
        s = __builtin_amdgcn_mfma_f32_16x16x32_bf16(aq0, bk0, s, 0, 0, 0);
        s = __builtin_amdgcn_mfma_f32_16x16x32_bf16(aq1, bk1, s, 0, 0, 0);
        #pragma unroll
        for (int r = 0; r < 4; r++) {
            const float v = s[r] * 0.125f + (float)Msm[quad * 4 + r][s0 + l16];
            sv[nt][r] = v;
            mx[r] = fmaxf(mx[r], v);
        }
    }
    // reduce max across the 16-lane key groups
    #pragma unroll
    for (int off = 1; off < 16; off <<= 1)
        #pragma unroll
        for (int r = 0; r < 4; r++)
            mx[r] = fmaxf(mx[r], __shfl_xor(mx[r], off, 64));
    if (l16 == 0)
        #pragma unroll
        for (int r = 0; r < 4; r++) redM[wave][quad * 4 + r] = mx[r];
    __syncthreads();
    float mf[4], sum[4] = {0.f, 0.f, 0.f, 0.f};
    #pragma unroll
    for (int r = 0; r < 4; r++) {
        const int qr = quad * 4 + r;
        mf[r] = fmaxf(fmaxf(redM[0][qr], redM[1][qr]),
                      fmaxf(redM[2][qr], redM[3][qr]));
    }
    #pragma unroll
    for (int nt = 0; nt < 8; nt++)
        #pragma unroll
        for (int r = 0; r < 4; r++) {
            const float e = __expf(sv[nt][r] - mf[r]);
            sv[nt][r] = e;
            sum[r] += e;
        }
    #pragma unroll
    for (int off = 1; off < 16; off <<= 1)
        #pragma unroll
        for (int r = 0; r < 4; r++)
            sum[r] += __shfl_xor(sum[r], off, 64);
    if (l16 == 0)
        #pragma unroll
        for (int r = 0; r < 4; r++) redS[wave][quad * 4 + r] = sum[r];
    __syncthreads();
    float inv[4];
    #pragma unroll
    for (int r = 0; r < 4; r++) {
        const int qr = quad * 4 + r;
        inv[r] = 1.f / (redS[0][qr] + redS[1][qr] + redS[2][qr] + redS[3][qr]);
    }
    #pragma unroll
    for (int nt = 0; nt < 8; nt++)
        #pragma unroll
        for (int r = 0; r < 4; r++)
            Psm[quad * 4 + r][wave * 128 + nt * 16 + l16] =
                (bf16)(sv[nt][r] * inv[r]);
    __syncthreads();

    // phase 2: X_tile = P @ V ; wave w computes d-range [w*16, w*16+16)
    const bf16* Vh = Vtws + (size_t)hd * 64 * 512;
    const int d0 = wave * 16;
    floatx4 o = {};
    #pragma unroll
    for (int ks = 0; ks < 16; ks++) {
        bf16x8 ap = *(const bf16x8*)(&Psm[l16][ks * 32 + quad * 8]);
        bf16x8 bv = *(const bf16x8*)(Vh + (size_t)(d0 + l16) * 512 + ks * 32 + quad * 8);
        o = __builtin_amdgcn_mfma_f32_16x16x32_bf16(ap, bv, o, 0, 0, 0);
    }
    #pragma unroll
    for (int r = 0; r < 4; r++) {
        const int q = quad * 4 + r;
        const size_t row = ((size_t)b * 512 + q0 + q) * 8 + c;
        Xws[row * 512 + h * 64 + d0 + l16] = (bf16)o[r];
    }
}

extern "C" void kernel_launch(void* const* d_in, const int* in_sizes, int n_in,
                              void* d_out, int out_size, void* d_ws, size_t ws_size,
                              hipStream_t stream)
{
    const float* qin  = (const float*)d_in[0];
    const float* kin  = (const float*)d_in[1];
    const float* vin  = (const float*)d_in[2];
    const int*   mask = (const int*)d_in[3];
    const float* Bq = (const float*)d_in[5];
    const float* Bk = (const float*)d_in[7];
    const float* Bv = (const float*)d_in[9];
    const float* Bo = (const float*)d_in[11];
    float* out = (float*)d_out;

    const size_t R = (size_t)8192 * 512;
    bf16* Xws  = (bf16*)d_ws;
    bf16* Qws  = Xws  + R;
    bf16* Kws  = Qws  + R;
    bf16* Vtws = Kws  + R;
    bf16* WT   = Vtws + R;

    wtr_kernel<<<dim3(8, 8, 4), dim3(256), 0, stream>>>(
        (const float*)d_in[4], (const float*)d_in[6],
        (const float*)d_in[8], (const float*)d_in[10], WT);
    qkv_kernel<<<dim3(128, 8, 3), dim3(256), 0, stream>>>(
        qin, kin, vin, WT, Bq, Bk, Bv, Qws, Kws, Vtws);
    attn_kernel<<<dim3(32, 128), dim3(256), 0, stream>>>(
        Qws, Kws, Vtws, mask, Xws);
    out_kernel<<<dim3(128, 8), dim3(256), 0, stream>>>(
        Xws, WT, Bo, out);
}

// Round 10
// 249.840 us; speedup vs baseline: 1.3538x; 1.3538x over previous
//
#include <hip/hip_runtime.h>
#include <hip/hip_bf16.h>

typedef __bf16 bf16;
typedef __bf16 bf16x8 __attribute__((ext_vector_type(8)));
typedef float floatx4 __attribute__((ext_vector_type(4)));

// B=2, T=512, C=8, D=512, H=8, dk=64. M = B*T*C = 8192.
// Inputs fp32 (dict order), output fp32.
// ws regions (R = 8192*512 bf16 = 8.39 MB): r0 r1 r2 r3 | WT (2 MB) = 35.6 MB
// (proven). Chain: cvt q,k,v -> r0,r1,r2 ; wtr -> WT ; gemmV r2->r3 ;
// gemmK r1->r2 ; gemmQ r0->r1 ; attn (r1,r2,r3)->r0 ; out r0 -> d_out.
// Q,K: [hd][t][d]; V^T: [hd][d][t]; hd = b*64+h*8+c.

#define AS1 __attribute__((address_space(1)))
#define AS3 __attribute__((address_space(3)))

__device__ __forceinline__ void gload_lds16(const bf16* g, bf16* l) {
    __builtin_amdgcn_global_load_lds((const AS1 unsigned int*)g,
                                     (AS3 unsigned int*)l, 16, 0, 0);
}

union Pack8 { bf16 h[8]; uint4 u; };

// ---------------- fp32 -> bf16 bulk convert: grid (2048, 3) x 256 ------------
__global__ __launch_bounds__(256) void cvt_kernel(
    const float* __restrict__ q, const float* __restrict__ k,
    const float* __restrict__ v,
    bf16* __restrict__ qa, bf16* __restrict__ ka, bf16* __restrict__ va)
{
    const float* src; bf16* dst;
    if (blockIdx.y == 0)      { src = q; dst = qa; }
    else if (blockIdx.y == 1) { src = k; dst = ka; }
    else                      { src = v; dst = va; }
    const size_t i = ((size_t)blockIdx.x * 256 + threadIdx.x) * 8;
    float4 a = *(const float4*)(src + i);
    float4 b = *(const float4*)(src + i + 4);
    Pack8 r;
    r.h[0] = (bf16)a.x; r.h[1] = (bf16)a.y; r.h[2] = (bf16)a.z; r.h[3] = (bf16)a.w;
    r.h[4] = (bf16)b.x; r.h[5] = (bf16)b.y; r.h[6] = (bf16)b.z; r.h[7] = (bf16)b.w;
    *(uint4*)(dst + i) = r.u;
}

// ---------------- weight transpose W[K][N] fp32 -> WT[N][K] bf16 -------------
__global__ __launch_bounds__(256) void wtr_kernel(
    const float* __restrict__ Wq, const float* __restrict__ Wk,
    const float* __restrict__ Wv, const float* __restrict__ Wo,
    bf16* __restrict__ WT)
{
    __shared__ float Ts[64][65];
    const int tid = threadIdx.x;
    const int k0 = blockIdx.x * 64;
    const int n0 = blockIdx.y * 64;
    const int z  = blockIdx.z;
    const float* W = (z == 0) ? Wq : (z == 1) ? Wk : (z == 2) ? Wv : Wo;
    bf16* O = WT + (size_t)z * 512 * 512;
    #pragma unroll
    for (int i = 0; i < 16; i++) {
        const int r = i * 4 + (tid >> 6), c = tid & 63;
        Ts[r][c] = W[(size_t)(k0 + r) * 512 + n0 + c];
    }
    __syncthreads();
    #pragma unroll
    for (int i = 0; i < 16; i++) {
        const int a = i * 4 + (tid >> 6), c = tid & 63;
        O[(size_t)(n0 + a) * 512 + k0 + c] = (bf16)Ts[c][a];
    }
}

// ---------------- m97-style GEMM: 128x128 tile, BK=32, global_load_lds -------
// A [8192][512] bf16, BT [512][512] bf16 (k-major). Block 256 = 4 waves,
// wave = 64x64 quadrant, acc[4][4]. LAYOUT 0: Q/K [hd][t][d]; 1: V^T
// [hd][d][t]; 2: fp32 row-major.
template<int LAYOUT, typename TO>
__global__ __launch_bounds__(256) void gemm_bt(
    const bf16* __restrict__ A, const bf16* __restrict__ BT,
    const float* __restrict__ bias, TO* __restrict__ out)
{
    __shared__ bf16 Asm[128 * 32];
    __shared__ bf16 Bsm[128 * 32];
    const int tid  = threadIdx.x;
    const int lane = tid & 63;
    const int wave = tid >> 6;
    const int quad = lane >> 4;
    const int l16  = lane & 15;
    const int mblk = blockIdx.x * 128;
    const int nblk = blockIdx.y * 128;

    // staging: wave w stages rows [w*16, w*16+16) and [64+w*16, ...) of each
    // tile; lane i -> row +i/4, col (i&3)*8 (matches HW lane*16B LDS scatter).
    const int srow = wave * 16 + (lane >> 2);
    const int scol = (lane & 3) * 8;
    const bf16* Ag0 = A + (size_t)(mblk + srow) * 512 + scol;
    const bf16* Ag1 = Ag0 + (size_t)64 * 512;
    const bf16* Bg0 = BT + (size_t)(nblk + srow) * 512 + scol;
    const bf16* Bg1 = Bg0 + (size_t)64 * 512;
    bf16* Al0 = Asm + wave * 16 * 32;
    bf16* Al1 = Asm + (64 + wave * 16) * 32;
    bf16* Bl0 = Bsm + wave * 16 * 32;
    bf16* Bl1 = Bsm + (64 + wave * 16) * 32;

    const int wr = (wave >> 1) * 64;
    const int wc = (wave & 1) * 64;

    floatx4 acc[4][4] = {};
    for (int k0 = 0; k0 < 512; k0 += 32) {
        gload_lds16(Ag0 + k0, Al0);
        gload_lds16(Ag1 + k0, Al1);
        gload_lds16(Bg0 + k0, Bl0);
        gload_lds16(Bg1 + k0, Bl1);
        __syncthreads();
        bf16x8 a[4], b[4];
        #pragma unroll
        for (int mt = 0; mt < 4; mt++)
            a[mt] = *(const bf16x8*)(Asm + (wr + mt * 16 + l16) * 32 + quad * 8);
        #pragma unroll
        for (int nt = 0; nt < 4; nt++)
            b[nt] = *(const bf16x8*)(Bsm + (wc + nt * 16 + l16) * 32 + quad * 8);
        #pragma unroll
        for (int mt = 0; mt < 4; mt++)
            #pragma unroll
            for (int nt = 0; nt < 4; nt++)
                acc[mt][nt] = __builtin_amdgcn_mfma_f32_16x16x32_bf16(
                    a[mt], b[nt], acc[mt][nt], 0, 0, 0);
        __syncthreads();
    }

    #pragma unroll
    for (int mt = 0; mt < 4; mt++) {
        #pragma unroll
        for (int nt = 0; nt < 4; nt++) {
            const int colg = nblk + wc + nt * 16 + l16;
            const float bb = bias[colg];
            #pragma unroll
            for (int r = 0; r < 4; r++) {
                const int rowg = mblk + wr + mt * 16 + quad * 4 + r;
                const float v = acc[mt][nt][r] + bb;
                if (LAYOUT == 2) {
                    out[(size_t)rowg * 512 + colg] = (TO)v;
                } else {
                    const int b_ = rowg >> 12;
                    const int t = (rowg >> 3) & 511;
                    const int c = rowg & 7;
                    const int h = colg >> 6;
                    const int d = colg & 63;
                    const int hd = b_ * 64 + h * 8 + c;
                    const size_t addr = (LAYOUT == 0)
                        ? ((size_t)hd * 512 + t) * 64 + d
                        : ((size_t)hd * 64 + d) * 512 + t;
                    out[addr] = (TO)v;
                }
            }
        }
    }
}

// ---------------- attention (round-9 version, proven) ------------------------
#define PST 520

__global__ __launch_bounds__(256) void attn_kernel(
    const bf16* __restrict__ Qws, const bf16* __restrict__ Kws,
    const bf16* __restrict__ Vtws, const int* __restrict__ mask,
    bf16* __restrict__ Xws)
{
    __shared__ bf16 Msm[16][PST];
    __shared__ bf16 Psm[16][PST];
    __shared__ float redM[4][16];
    __shared__ float redS[4][16];
    const int tid  = threadIdx.x;
    const int wave = tid >> 6;
    const int lane = tid & 63;
    const int quad = lane >> 4;
    const int l16  = lane & 15;
    const int qt = blockIdx.x;
    const int hd = blockIdx.y;
    const int q0 = qt * 16;
    const int b = hd >> 6;
    const int h = (hd >> 3) & 7;
    const int c = hd & 7;

    {
        const int* mp = mask + ((size_t)b * 512 + q0) * 512;
        #pragma unroll
        for (int it = 0; it < 8; it++) {
            const int idx = (it * 256 + tid) * 4;
            const int4 mv = *(const int4*)(mp + idx);
            const int row = idx >> 9, col = idx & 511;
            union { bf16 h[4]; unsigned long long u; } pk;
            pk.h[0] = (mv.x == 0) ? (bf16)(-1.0e9f) : (bf16)0.0f;
            pk.h[1] = (mv.y == 0) ? (bf16)(-1.0e9f) : (bf16)0.0f;
            pk.h[2] = (mv.z == 0) ? (bf16)(-1.0e9f) : (bf16)0.0f;
            pk.h[3] = (mv.w == 0) ? (bf16)(-1.0e9f) : (bf16)0.0f;
            *(unsigned long long*)&Msm[row][col] = pk.u;
        }
    }

    const bf16* Qh = Qws + (size_t)hd * 512 * 64;
    const bf16* Kh = Kws + (size_t)hd * 512 * 64;
    bf16x8 aq0 = *(const bf16x8*)(Qh + (size_t)(q0 + l16) * 64 + quad * 8);
    bf16x8 aq1 = *(const bf16x8*)(Qh + (size_t)(q0 + l16) * 64 + 32 + quad * 8);
    __syncthreads();

    float sv[8][4];
    float mx[4] = {-3.0e38f, -3.0e38f, -3.0e38f, -3.0e38f};
    #pragma unroll
    for (int nt = 0; nt < 8; nt++) {
        const int s0 = wave * 128 + nt * 16;
        bf16x8 bk0 = *(const bf16x8*)(Kh + (size_t)(s0 + l16) * 64 + quad * 8);
        bf16x8 bk1 = *(const bf16x8*)(Kh + (size_t)(s0 + l16) * 64 + 32 + quad * 8);
        floatx4 s = {};
        s = __builtin_amdgcn_mfma_f32_16x16x32_bf16(aq0, bk0, s, 0, 0, 0);
        s = __builtin_amdgcn_mfma_f32_16x16x32_bf16(aq1, bk1, s, 0, 0, 0);
        #pragma unroll
        for (int r = 0; r < 4; r++) {
            const float v = s[r] * 0.125f + (float)Msm[quad * 4 + r][s0 + l16];
            sv[nt][r] = v;
            mx[r] = fmaxf(mx[r], v);
        }
    }
    #pragma unroll
    for (int off = 1; off < 16; off <<= 1)
        #pragma unroll
        for (int r = 0; r < 4; r++)
            mx[r] = fmaxf(mx[r], __shfl_xor(mx[r], off, 64));
    if (l16 == 0)
        #pragma unroll
        for (int r = 0; r < 4; r++) redM[wave][quad * 4 + r] = mx[r];
    __syncthreads();
    float mf[4], sum[4] = {0.f, 0.f, 0.f, 0.f};
    #pragma unroll
    for (int r = 0; r < 4; r++) {
        const int qr = quad * 4 + r;
        mf[r] = fmaxf(fmaxf(redM[0][qr], redM[1][qr]),
                      fmaxf(redM[2][qr], redM[3][qr]));
    }
    #pragma unroll
    for (int nt = 0; nt < 8; nt++)
        #pragma unroll
        for (int r = 0; r < 4; r++) {
            const float e = __expf(sv[nt][r] - mf[r]);
            sv[nt][r] = e;
            sum[r] += e;
        }
    #pragma unroll
    for (int off = 1; off < 16; off <<= 1)
        #pragma unroll
        for (int r = 0; r < 4; r++)
            sum[r] += __shfl_xor(sum[r], off, 64);
    if (l16 == 0)
        #pragma unroll
        for (int r = 0; r < 4; r++) redS[wave][quad * 4 + r] = sum[r];
    __syncthreads();
    float inv[4];
    #pragma unroll
    for (int r = 0; r < 4; r++) {
        const int qr = quad * 4 + r;
        inv[r] = 1.f / (redS[0][qr] + redS[1][qr] + redS[2][qr] + redS[3][qr]);
    }
    #pragma unroll
    for (int nt = 0; nt < 8; nt++)
        #pragma unroll
        for (int r = 0; r < 4; r++)
            Psm[quad * 4 + r][wave * 128 + nt * 16 + l16] =
                (bf16)(sv[nt][r] * inv[r]);
    __syncthreads();

    const bf16* Vh = Vtws + (size_t)hd * 64 * 512;
    const int d0 = wave * 16;
    floatx4 o = {};
    #pragma unroll
    for (int ks = 0; ks < 16; ks++) {
        bf16x8 ap = *(const bf16x8*)(&Psm[l16][ks * 32 + quad * 8]);
        bf16x8 bv = *(const bf16x8*)(Vh + (size_t)(d0 + l16) * 512 + ks * 32 + quad * 8);
        o = __builtin_amdgcn_mfma_f32_16x16x32_bf16(ap, bv, o, 0, 0, 0);
    }
    #pragma unroll
    for (int r = 0; r < 4; r++) {
        const int q = quad * 4 + r;
        const size_t row = ((size_t)b * 512 + q0 + q) * 8 + c;
        Xws[row * 512 + h * 64 + d0 + l16] = (bf16)o[r];
    }
}

extern "C" void kernel_launch(void* const* d_in, const int* in_sizes, int n_in,
                              void* d_out, int out_size, void* d_ws, size_t ws_size,
                              hipStream_t stream)
{
    const float* qin  = (const float*)d_in[0];
    const float* kin  = (const float*)d_in[1];
    const float* vin  = (const float*)d_in[2];
    const int*   mask = (const int*)d_in[3];
    const float* Bq = (const float*)d_in[5];
    const float* Bk = (const float*)d_in[7];
    const float* Bv = (const float*)d_in[9];
    const float* Bo = (const float*)d_in[11];
    float* out = (float*)d_out;

    const size_t R = (size_t)8192 * 512;
    bf16* r0 = (bf16*)d_ws;
    bf16* r1 = r0 + R;
    bf16* r2 = r1 + R;
    bf16* r3 = r2 + R;
    bf16* WT = r3 + R;

    cvt_kernel<<<dim3(2048, 3), dim3(256), 0, stream>>>(
        qin, kin, vin, r0, r1, r2);
    wtr_kernel<<<dim3(8, 8, 4), dim3(256), 0, stream>>>(
        (const float*)d_in[4], (const float*)d_in[6],
        (const float*)d_in[8], (const float*)d_in[10], WT);
    gemm_bt<1, bf16><<<dim3(64, 4), dim3(256), 0, stream>>>(
        r2, WT + (size_t)2 * 262144, Bv, r3);          // V^T
    gemm_bt<0, bf16><<<dim3(64, 4), dim3(256), 0, stream>>>(
        r1, WT + (size_t)1 * 262144, Bk, r2);          // K
    gemm_bt<0, bf16><<<dim3(64, 4), dim3(256), 0, stream>>>(
        r0, WT + (size_t)0 * 262144, Bq, r1);          // Q
    attn_kernel<<<dim3(32, 128), dim3(256), 0, stream>>>(
        r1, r2, r3, mask, r0);
    gemm_bt<2, float><<<dim3(64, 4), dim3(256), 0, stream>>>(
        r0, WT + (size_t)3 * 262144, Bo, out);
}